// Round 9
// baseline (570.659 us; speedup 1.0000x reference)
//
#include <hip/hip_runtime.h>

typedef __attribute__((ext_vector_type(8))) short v8s;
typedef __attribute__((ext_vector_type(4))) float v4f;

#define MB 16          // batches per workgroup (1 MFMA row-tile)
#define B_TOT 8192
#define GP 17          // gbuf padded stride (batch dim)

// ws ushort offsets (bf16 fragment regions) — layout identical to rounds 3-8
#define BL0_U 0        // [n16][kst2][s2][lane64][e8] : 32768 ushorts (Whh0)
#define BL1_U 32768    // [n16][kst4][s2][lane64][e8] : 65536 ushorts (Wih1|Whh1)
#define BFC_U 98304    // [kst2][s2][lane64][e8]      : 2048 ushorts  (Wfc, 13 zero cols)
#define NUSH  100352
#define B0_F  50176    // bih0+bhh0 : 256
#define B1_F  50432    // bih1+bhh1 : 256
#define BFC3_F 50688   // bfc : 3

__device__ __forceinline__ unsigned short f2bh(float f) {
    unsigned u = __float_as_uint(f);
    return (unsigned short)((u + 0x7fffu + ((u >> 16) & 1u)) >> 16);   // RNE to bf16
}
__device__ __forceinline__ float bh2f(unsigned short h) {
    return __uint_as_float(((unsigned)h) << 16);
}
__device__ __forceinline__ float sigm(float x) {
    return 1.f / (1.f + __expf(-x));
}
__device__ __forceinline__ float tanh_(float x) {
    float e = __expf(-2.f * fabsf(x));
    float r = (1.f - e) / (1.f + e);
    return copysignf(r, x);
}
__device__ __forceinline__ v8s ldfrag(const unsigned short* p) { return *(const v8s*)p; }

#define MFMA(a, b, c) __builtin_amdgcn_mfma_f32_16x16x32_bf16((a), (b), (c), 0, 0, 0)

// ---------------------------------------------------------------------------
// repack: UNCHANGED (HW-verified correct in rounds 3/5/7/8)
// ---------------------------------------------------------------------------
__global__ void repack(const float* __restrict__ Whh0,
                       const float* __restrict__ bih0, const float* __restrict__ bhh0,
                       const float* __restrict__ Wih1, const float* __restrict__ Whh1,
                       const float* __restrict__ bih1, const float* __restrict__ bhh1,
                       const float* __restrict__ Wfc,  const float* __restrict__ bfc,
                       float* __restrict__ wsf) {
    unsigned idx = blockIdx.x * 256 + threadIdx.x;
    unsigned short* wsu = (unsigned short*)wsf;
    if (idx < NUSH) {
        unsigned u, fid, l, e, s, kst, n, r, k;
        float wv;
        if (idx < BL1_U) {
            u = idx; fid = u >> 9; l = (u >> 3) & 63; e = u & 7;
            s = fid & 1; unsigned t = fid >> 1; kst = t & 1; n = t >> 1;
            r = n * 16 + (l & 15); k = kst * 32 + ((l >> 4) * 8) + e;
            wv = Whh0[r * 64 + k];
        } else if (idx < BFC_U) {
            u = idx - BL1_U; fid = u >> 9; l = (u >> 3) & 63; e = u & 7;
            s = fid & 1; unsigned t = fid >> 1; kst = t & 3; n = t >> 2;
            r = n * 16 + (l & 15); k = kst * 32 + ((l >> 4) * 8) + e;
            wv = (k < 64) ? Wih1[r * 64 + k] : Whh1[r * 64 + (k - 64)];
        } else {
            u = idx - BFC_U; fid = u >> 9; l = (u >> 3) & 63; e = u & 7;
            s = fid & 1; kst = fid >> 1;
            unsigned o = l & 15; k = kst * 32 + ((l >> 4) * 8) + e;
            wv = (o < 3) ? Wfc[o * 64 + k] : 0.f;
        }
        unsigned short hi = f2bh(wv);
        wsu[idx] = s ? f2bh(wv - bh2f(hi)) : hi;
    } else {
        unsigned jj = idx - NUSH;
        if (jj < 256) wsf[B0_F + jj] = bih0[jj] + bhh0[jj];
        else if (jj < 512) wsf[B1_F + (jj - 256)] = bih1[jj - 256] + bhh1[jj - 256];
        else if (jj < 515) wsf[BFC3_F + (jj - 512)] = bfc[jj - 512];
    }
}

// ---------------------------------------------------------------------------
// main kernel: 512 wgs x 256 thr (4 waves), 16 batches/wg → 2 INDEPENDENT
// wg/CU (LDS 34 KB permits 4). All weights streamed from L2 per use — the
// round-8-proven spill-proof structure — while the 2 co-resident wgs overlap
// phases (one in MFMA while the other runs activations / waits on loads).
// Wave w owns col-tiles {4w..4w+3}.
// ---------------------------------------------------------------------------
__global__ __launch_bounds__(256)
void lstm_main(
    const float* __restrict__ x0, const float* __restrict__ h_init,
    const float* __restrict__ c_init, const float* __restrict__ Wih0,
    const float* __restrict__ wsf, const int* __restrict__ nsp,
    float* __restrict__ out)
{
    // h tiles in MFMA A-frag order: [buf][split][khalf][512]
    __shared__ __align__(16) unsigned short Th0[2][2][2][512];   // 8 KB
    __shared__ __align__(16) unsigned short Th1[2][2][2][512];   // 8 KB
    __shared__ float gbuf[256][GP];                               // 17 KB
    __shared__ __align__(16) float xs[2][MB][4];                  // 0.5 KB

    const unsigned short* wsu = (const unsigned short*)wsf;
    const int tid = threadIdx.x, l = tid & 63, w = tid >> 6;   // w: 0..3
    const int b0g = blockIdx.x * MB;
    const int n = nsp[0];
    const int n0 = 4 * w;                    // first of this wave's 4 col-tiles
    const int c15 = l & 15;
    const int bfirst = (l >> 4) * 4;         // first D row (batch) of this lane
    // activation mapping: thread owns batch ab, hidden units ajb..ajb+3
    const int ab = tid & 15;                 // batch 0..15
    const int ajb = (tid >> 4) * 4;          // j base (0,4,...,60)

    float bias0[4], bias1[4], wx[4][3];
#pragma unroll
    for (int nt = 0; nt < 4; ++nt) {
        const int cc = (n0 + nt) * 16 + c15;
        bias0[nt] = wsf[B0_F + cc];
        bias1[nt] = wsf[B1_F + cc];
#pragma unroll
        for (int oi = 0; oi < 3; ++oi) wx[nt][oi] = Wih0[cc * 3 + oi];
    }
    const float mybfc = (c15 < 3) ? wsf[BFC3_F + c15] : 0.f;
    // precomputed output addresses for the FC-writer lanes (wave 0, c15<3)
    int outbase[4];
    {
        const int n3 = n * 3;
#pragma unroll
        for (int r = 0; r < 4; ++r)
            outbase[r] = (b0g + bfirst + r) * n3 + c15;
    }

    // ---- init state (activation mapping) ----
    float c0[4], c1[4];
    {
        const int bg = b0g + ab;
#pragma unroll
        for (int m = 0; m < 4; ++m) {
            const int jj = ajb + m;
            c0[m] = c_init[bg * 64 + jj];
            c1[m] = c_init[B_TOT * 64 + bg * 64 + jj];
            float h0v = h_init[bg * 64 + jj];
            float h1v = h_init[B_TOT * 64 + bg * 64 + jj];
            const int kh = jj >> 5, kl = jj & 31;
            const int idx = ((kl >> 3) << 7) + (ab << 3) + (kl & 7);
            unsigned short hh = f2bh(h0v);
            Th0[0][0][kh][idx] = hh;
            Th0[0][1][kh][idx] = f2bh(h0v - bh2f(hh));
            hh = f2bh(h1v);
            Th1[0][0][kh][idx] = hh;
            Th1[0][1][kh][idx] = f2bh(h1v - bh2f(hh));
        }
    }
    if (tid < MB * 3) {
        int b = tid / 3, o = tid % 3;
        xs[0][b][o] = x0[(b0g + b) * 3 + o];
    }
    __syncthreads();

    int cur = 0;
    for (int t = 0; t < n; ++t) {
        const int nxt = cur ^ 1;
        // ================= Phase A: layer-0 matmul =================
        {
            v4f acc[4];
#pragma unroll
            for (int nt = 0; nt < 4; ++nt)
                acc[nt] = (v4f){bias0[nt], bias0[nt], bias0[nt], bias0[nt]};
            // exact-fp32 input part (K=3)
#pragma unroll
            for (int r = 0; r < 4; ++r) {
                float4 xv = *(const float4*)&xs[cur][bfirst + r][0];
#pragma unroll
                for (int nt = 0; nt < 4; ++nt)
                    acc[nt][r] += wx[nt][0] * xv.x + wx[nt][1] * xv.y + wx[nt][2] * xv.z;
            }
            // recurrent part: stream B hi+lo from L2 per kstep
#pragma unroll
            for (int k = 0; k < 2; ++k) {
                v8s bh[4], bl[4];
#pragma unroll
                for (int nt = 0; nt < 4; ++nt) {
                    bh[nt] = ldfrag(wsu + BL0_U + ((((n0 + nt) * 2 + k) * 2 + 0) << 9) + (l << 3));
                    bl[nt] = ldfrag(wsu + BL0_U + ((((n0 + nt) * 2 + k) * 2 + 1) << 9) + (l << 3));
                }
                v8s ah = *(const v8s*)&Th0[cur][0][k][l * 8];
                v8s al = *(const v8s*)&Th0[cur][1][k][l * 8];
#pragma unroll
                for (int nt = 0; nt < 4; ++nt) {
                    acc[nt] = MFMA(ah, bh[nt], acc[nt]);
                    acc[nt] = MFMA(al, bh[nt], acc[nt]);
                    acc[nt] = MFMA(ah, bl[nt], acc[nt]);
                }
            }
#pragma unroll
            for (int nt = 0; nt < 4; ++nt)
#pragma unroll
                for (int r = 0; r < 4; ++r)
                    gbuf[(n0 + nt) * 16 + c15][bfirst + r] = acc[nt][r];
        }
        __syncthreads();                     // B1: gates-L0 visible

        // ================= Phase B: layer-0 activations =================
#pragma unroll
        for (int m = 0; m < 4; ++m) {
            const int jj = ajb + m;
            float ig = sigm(gbuf[jj][ab]);
            float fg = sigm(gbuf[64 + jj][ab]);
            float gg = tanh_(gbuf[128 + jj][ab]);
            float og = sigm(gbuf[192 + jj][ab]);
            float cn = fg * c0[m] + ig * gg;
            c0[m] = cn;
            float h = og * tanh_(cn);
            unsigned short hh = f2bh(h);
            const int kh = jj >> 5, kl = jj & 31;
            const int idx = ((kl >> 3) << 7) + (ab << 3) + (kl & 7);
            Th0[nxt][0][kh][idx] = hh;
            Th0[nxt][1][kh][idx] = f2bh(h - bh2f(hh));
        }
        __syncthreads();                     // B2: h0_new frags visible

        // ================= Phase C: layer-1 matmul =================
        {
            v4f acc[4];
#pragma unroll
            for (int nt = 0; nt < 4; ++nt)
                acc[nt] = (v4f){bias1[nt], bias1[nt], bias1[nt], bias1[nt]};
#pragma unroll
            for (int k = 0; k < 4; ++k) {
                v8s bh[4], bl[4];
#pragma unroll
                for (int nt = 0; nt < 4; ++nt) {
                    bh[nt] = ldfrag(wsu + BL1_U + ((((n0 + nt) * 4 + k) * 2 + 0) << 9) + (l << 3));
                    bl[nt] = ldfrag(wsu + BL1_U + ((((n0 + nt) * 4 + k) * 2 + 1) << 9) + (l << 3));
                }
                v8s ah, al;
                if (k < 2) { ah = *(const v8s*)&Th0[nxt][0][k][l * 8];
                             al = *(const v8s*)&Th0[nxt][1][k][l * 8]; }
                else       { ah = *(const v8s*)&Th1[cur][0][k - 2][l * 8];
                             al = *(const v8s*)&Th1[cur][1][k - 2][l * 8]; }
#pragma unroll
                for (int nt = 0; nt < 4; ++nt) {
                    acc[nt] = MFMA(ah, bh[nt], acc[nt]);
                    acc[nt] = MFMA(al, bh[nt], acc[nt]);
                    acc[nt] = MFMA(ah, bl[nt], acc[nt]);
                }
            }
#pragma unroll
            for (int nt = 0; nt < 4; ++nt)
#pragma unroll
                for (int r = 0; r < 4; ++r)
                    gbuf[(n0 + nt) * 16 + c15][bfirst + r] = acc[nt][r];
        }
        __syncthreads();                     // B3: gates-L1 visible

        // ================= Phase D: layer-1 activations =================
#pragma unroll
        for (int m = 0; m < 4; ++m) {
            const int jj = ajb + m;
            float ig = sigm(gbuf[jj][ab]);
            float fg = sigm(gbuf[64 + jj][ab]);
            float gg = tanh_(gbuf[128 + jj][ab]);
            float og = sigm(gbuf[192 + jj][ab]);
            float cn = fg * c1[m] + ig * gg;
            c1[m] = cn;
            float h = og * tanh_(cn);
            unsigned short hh = f2bh(h);
            const int kh = jj >> 5, kl = jj & 31;
            const int idx = ((kl >> 3) << 7) + (ab << 3) + (kl & 7);
            Th1[nxt][0][kh][idx] = hh;
            Th1[nxt][1][kh][idx] = f2bh(h - bh2f(hh));
        }
        __syncthreads();                     // B4: h1_new frags visible

        // ================= Phase E: FC head (wave 0), direct out store =====
        if (w == 0) {
            v8s bfh[2], bfl[2];
#pragma unroll
            for (int k = 0; k < 2; ++k) {
                bfh[k] = ldfrag(wsu + BFC_U + ((k * 2 + 0) << 9) + (l << 3));
                bfl[k] = ldfrag(wsu + BFC_U + ((k * 2 + 1) << 9) + (l << 3));
            }
            v4f af = (v4f){mybfc, mybfc, mybfc, mybfc};
#pragma unroll
            for (int k = 0; k < 2; ++k) {
                v8s ah = *(const v8s*)&Th1[nxt][0][k][l * 8];
                v8s al = *(const v8s*)&Th1[nxt][1][k][l * 8];
                af = MFMA(ah, bfh[k], af);
                af = MFMA(al, bfh[k], af);
                af = MFMA(ah, bfl[k], af);
            }
            if (c15 < 3) {
#pragma unroll
                for (int r = 0; r < 4; ++r) {
                    float v = af[r];
                    out[outbase[r] + t * 3] = v;
                    xs[nxt][bfirst + r][c15] = v;   // feedback input for next step
                }
            }
        }
        __syncthreads();                     // B5: x_next + buffers settled
        cur = nxt;
    }
}

extern "C" void kernel_launch(void* const* d_in, const int* in_sizes, int n_in,
                              void* d_out, int out_size, void* d_ws, size_t ws_size,
                              hipStream_t stream) {
    const float* x    = (const float*)d_in[0];
    const float* hid  = (const float*)d_in[1];
    const float* cel  = (const float*)d_in[2];
    const float* Wih0 = (const float*)d_in[3];
    const float* Whh0 = (const float*)d_in[4];
    const float* bih0 = (const float*)d_in[5];
    const float* bhh0 = (const float*)d_in[6];
    const float* Wih1 = (const float*)d_in[7];
    const float* Whh1 = (const float*)d_in[8];
    const float* bih1 = (const float*)d_in[9];
    const float* bhh1 = (const float*)d_in[10];
    const float* Wfc  = (const float*)d_in[11];
    const float* bfc  = (const float*)d_in[12];
    const int*   nst  = (const int*)d_in[13];
    float* ws  = (float*)d_ws;
    float* outp = (float*)d_out;

    const int repack_threads = NUSH + 515;
    repack<<<(repack_threads + 255) / 256, 256, 0, stream>>>(
        Whh0, bih0, bhh0, Wih1, Whh1, bih1, bhh1, Wfc, bfc, ws);
    lstm_main<<<B_TOT / MB, 256, 0, stream>>>(x, hid, cel, Wih0, ws, nst, outp);
}

// Round 13
// 352.897 us; speedup vs baseline: 1.6171x; 1.6171x over previous
//
#include <hip/hip_runtime.h>

typedef __attribute__((ext_vector_type(8))) _Float16 v8h;
typedef __attribute__((ext_vector_type(4))) float v4f;

#define MB 16
#define B_TOT 8192

// f16 fragment regions (half-index offsets into ws)
#define L0_H 0        // [nt16][kst2][lane64][e8] : 16384 halves (Whh0)
#define L1_H 16384    // [nt16][kst4][lane64][e8] : 32768 halves (Wih1|Whh1)
#define FC_H 49152    // [kst2][lane64][e8]       : 1024 halves  (Wfc, 13 zero cols)
#define NHALF 50176   // == 25088 floats
#define B0_F 25088    // bih0+bhh0 : 256 floats
#define B1_F 25344    // bih1+bhh1 : 256
#define BFC3_F 25600  // bfc : 3

__device__ __forceinline__ float sigm(float x) {
    return 1.f / (1.f + __expf(-x));
}
__device__ __forceinline__ float tanh_(float x) {
    float e = __expf(-2.f * fabsf(x));
    float r = (1.f - e) / (1.f + e);
    return copysignf(r, x);
}

#define MFMAH(a, b, c) __builtin_amdgcn_mfma_f32_16x16x32_f16((a), (b), (c), 0, 0, 0)

// ---------------------------------------------------------------------------
// repack: f16 single-precision fragments (B-frag layout: lane L holds
// B[k=(L>>4)*8+e][col=L&15], col_global = nt*16 + (L&15) = output row r)
// ---------------------------------------------------------------------------
__global__ void repack(const float* __restrict__ Whh0,
                       const float* __restrict__ bih0, const float* __restrict__ bhh0,
                       const float* __restrict__ Wih1, const float* __restrict__ Whh1,
                       const float* __restrict__ bih1, const float* __restrict__ bhh1,
                       const float* __restrict__ Wfc,  const float* __restrict__ bfc,
                       float* __restrict__ wsf) {
    unsigned idx = blockIdx.x * 256 + threadIdx.x;
    _Float16* wsh = (_Float16*)wsf;
    if (idx < NHALF) {
        unsigned l = (idx >> 3) & 63, e = idx & 7;
        float wv;
        if (idx < L1_H) {                   // layer-0: Whh0, K=64 (2 ksteps)
            unsigned fid = idx >> 9, nt = fid >> 1, kst = fid & 1;
            unsigned r = nt * 16 + (l & 15), k = kst * 32 + ((l >> 4) << 3) + e;
            wv = Whh0[r * 64 + k];
        } else if (idx < FC_H) {            // layer-1: [Wih1|Whh1], K=128 (4 ksteps)
            unsigned u = idx - L1_H, fid = u >> 9, nt = fid >> 2, kst = fid & 3;
            unsigned r = nt * 16 + (l & 15), k = kst * 32 + ((l >> 4) << 3) + e;
            wv = (k < 64) ? Wih1[r * 64 + k] : Whh1[r * 64 + (k - 64)];
        } else {                            // FC: Wfc, K=64 (2 ksteps), 13 zero cols
            unsigned u = idx - FC_H, kst = u >> 9;
            unsigned o = l & 15, k = kst * 32 + ((l >> 4) << 3) + e;
            wv = (o < 3) ? Wfc[o * 64 + k] : 0.f;
        }
        wsh[idx] = (_Float16)wv;
    } else {
        unsigned jj = idx - NHALF;
        if (jj < 256) wsf[B0_F + jj] = bih0[jj] + bhh0[jj];
        else if (jj < 512) wsf[B1_F + (jj - 256)] = bih1[jj - 256] + bhh1[jj - 256];
        else if (jj < 515) wsf[BFC3_F + (jj - 512)] = bfc[jj - 512];
    }
}

// ---------------------------------------------------------------------------
// main kernel: 512 wgs x 256 thr (4 waves), 16 batches/wg, 2 wg/CU.
// Gate-grouped ownership: wave w owns ntiles {w,4+w,8+w,12+w} = all 4 gates
// of units [16w,16w+16). All weights persistent in registers (f16, 26 frags
// = 104 VGPRs); activations fully in-lane; 2 barriers/step; FC redundant on
// all waves with register x-feedback via in-wave shuffles.
// ---------------------------------------------------------------------------
__global__ __launch_bounds__(256)
void lstm_main(
    const float* __restrict__ x0, const float* __restrict__ h_init,
    const float* __restrict__ c_init, const float* __restrict__ Wih0,
    const float* __restrict__ wsf, const int* __restrict__ nsp,
    float* __restrict__ out)
{
    // h state, MFMA A-frag order: [buf][khalf][ (k&31>>3)<<7 | b<<3 | k&7 ]
    __shared__ _Float16 Th0[2][2][512];     // 4 KB
    __shared__ _Float16 Th1[2][2][512];     // 4 KB

    const _Float16* wsh = (const _Float16*)wsf;
    const int tid = threadIdx.x, l = tid & 63, w = tid >> 6;   // w: 0..3
    const int b0g = blockIdx.x * MB;
    const int n = nsp[0];
    const int c15 = l & 15;
    const int bfirst = (l >> 4) * 4;         // lane's 4 batches: bfirst..bfirst+3
    const int j = 16 * w + c15;              // lane's hidden unit
    const int kh = j >> 5, kl = j & 31;
    const int hwoff = ((kl >> 3) << 7) + (bfirst << 3) + (kl & 7);   // + r*8
    const int sbase = l & 48;                // shuffle source base ((l>>4)<<4)

    // ---- persistent f16 weight fragments (104 VGPRs) ----
    v8h wb0[4][2], wb1[4][4], wfc2[2];
#pragma unroll
    for (int g = 0; g < 4; ++g) {
        const int nt = 4 * g + w;
#pragma unroll
        for (int k = 0; k < 2; ++k)
            wb0[g][k] = *(const v8h*)(wsh + L0_H + ((nt * 2 + k) << 9) + (l << 3));
#pragma unroll
        for (int k = 0; k < 4; ++k)
            wb1[g][k] = *(const v8h*)(wsh + L1_H + ((nt * 4 + k) << 9) + (l << 3));
    }
#pragma unroll
    for (int k = 0; k < 2; ++k)
        wfc2[k] = *(const v8h*)(wsh + FC_H + (k << 9) + (l << 3));

    float bias0[4], bias1[4];
    v8h wxp0 = {}, wxp1 = {};               // 12 Wih0 weights, f16-packed
#pragma unroll
    for (int g = 0; g < 4; ++g) {
        const int cc = 64 * g + j;
        bias0[g] = wsf[B0_F + cc];
        bias1[g] = wsf[B1_F + cc];
#pragma unroll
        for (int o = 0; o < 3; ++o) {
            const int ii = g * 3 + o;
            _Float16 v = (_Float16)Wih0[cc * 3 + o];
            if (ii < 8) wxp0[ii] = v; else wxp1[ii - 8] = v;
        }
    }
    const float mybfc = (c15 < 3) ? wsf[BFC3_F + c15] : 0.f;

    // ---- init state (MFMA mapping: lane owns (j, 4 batches)) ----
    float c0[4], c1[4];
    v4f af;
    int ob[4];
    {
        const int n3 = n * 3;
#pragma unroll
        for (int r = 0; r < 4; ++r) {
            const int bg = b0g + bfirst + r;
            c0[r] = c_init[bg * 64 + j];
            c1[r] = c_init[B_TOT * 64 + bg * 64 + j];
            Th0[0][kh][hwoff + r * 8] = (_Float16)h_init[bg * 64 + j];
            Th1[0][kh][hwoff + r * 8] = (_Float16)h_init[B_TOT * 64 + bg * 64 + j];
            af[r] = (c15 < 3) ? x0[bg * 3 + c15] : 0.f;
            ob[r] = bg * n3 + c15;
        }
    }
    __syncthreads();

    int cur = 0;
    for (int t = 0; t < n; ++t) {
        const int nxt = cur ^ 1;
        // ================= Phase A: layer-0 matmul + in-lane activations ====
        {
            v4f acc[4];
#pragma unroll
            for (int g = 0; g < 4; ++g)
                acc[g] = (v4f){bias0[g], bias0[g], bias0[g], bias0[g]};
            // input part (K=3), x gathered from af via in-wave shfl
#pragma unroll
            for (int r = 0; r < 4; ++r) {
#pragma unroll
                for (int o = 0; o < 3; ++o) {
                    float xv = __shfl(af[r], sbase | o);
#pragma unroll
                    for (int g = 0; g < 4; ++g) {
                        const int ii = g * 3 + o;
                        float wgt = (ii < 8) ? (float)wxp0[ii] : (float)wxp1[ii - 8];
                        acc[g][r] += wgt * xv;
                    }
                }
            }
            // recurrent part: A from LDS, persistent B
#pragma unroll
            for (int k = 0; k < 2; ++k) {
                v8h ah = *(const v8h*)&Th0[cur][k][l * 8];
#pragma unroll
                for (int g = 0; g < 4; ++g) acc[g] = MFMAH(ah, wb0[g][k], acc[g]);
            }
            // layer-0 cell update, all gates in-lane
#pragma unroll
            for (int r = 0; r < 4; ++r) {
                float ig = sigm(acc[0][r]), fg = sigm(acc[1][r]);
                float gg = tanh_(acc[2][r]), og = sigm(acc[3][r]);
                float cn = fg * c0[r] + ig * gg;
                c0[r] = cn;
                Th0[nxt][kh][hwoff + r * 8] = (_Float16)(og * tanh_(cn));
            }
        }
        __syncthreads();                     // B2: h0_new visible

        // ================= Phase C: layer-1 matmul + in-lane activations ====
        {
            v4f acc[4];
#pragma unroll
            for (int g = 0; g < 4; ++g)
                acc[g] = (v4f){bias1[g], bias1[g], bias1[g], bias1[g]};
#pragma unroll
            for (int k = 0; k < 4; ++k) {
                v8h ah = (k < 2) ? *(const v8h*)&Th0[nxt][k][l * 8]
                                 : *(const v8h*)&Th1[cur][k - 2][l * 8];
#pragma unroll
                for (int g = 0; g < 4; ++g) acc[g] = MFMAH(ah, wb1[g][k], acc[g]);
            }
#pragma unroll
            for (int r = 0; r < 4; ++r) {
                float ig = sigm(acc[0][r]), fg = sigm(acc[1][r]);
                float gg = tanh_(acc[2][r]), og = sigm(acc[3][r]);
                float cn = fg * c1[r] + ig * gg;
                c1[r] = cn;
                Th1[nxt][kh][hwoff + r * 8] = (_Float16)(og * tanh_(cn));
            }
        }
        __syncthreads();                     // B4: h1_new visible

        // ====== Phase E: FC head, redundant on all waves (register x-fb) ====
        {
            v4f afv = (v4f){mybfc, mybfc, mybfc, mybfc};
#pragma unroll
            for (int k = 0; k < 2; ++k) {
                v8h ah = *(const v8h*)&Th1[nxt][k][l * 8];
                afv = MFMAH(ah, wfc2[k], afv);
            }
            af = afv;                        // next step's x (via shuffles)
            if (w == 0 && c15 < 3) {
#pragma unroll
                for (int r = 0; r < 4; ++r)
                    out[ob[r] + t * 3] = afv[r];
            }
        }
        cur = nxt;                           // no barrier needed (race-proof traced)
    }
}

extern "C" void kernel_launch(void* const* d_in, const int* in_sizes, int n_in,
                              void* d_out, int out_size, void* d_ws, size_t ws_size,
                              hipStream_t stream) {
    const float* x    = (const float*)d_in[0];
    const float* hid  = (const float*)d_in[1];
    const float* cel  = (const float*)d_in[2];
    const float* Wih0 = (const float*)d_in[3];
    const float* Whh0 = (const float*)d_in[4];
    const float* bih0 = (const float*)d_in[5];
    const float* bhh0 = (const float*)d_in[6];
    const float* Wih1 = (const float*)d_in[7];
    const float* Whh1 = (const float*)d_in[8];
    const float* bih1 = (const float*)d_in[9];
    const float* bhh1 = (const float*)d_in[10];
    const float* Wfc  = (const float*)d_in[11];
    const float* bfc  = (const float*)d_in[12];
    const int*   nst  = (const int*)d_in[13];
    float* ws  = (float*)d_ws;
    float* outp = (float*)d_out;

    const int repack_threads = NHALF + 515;
    repack<<<(repack_threads + 255) / 256, 256, 0, stream>>>(
        Whh0, bih0, bhh0, Wih1, Whh1, bih1, bhh1, Wfc, bfc, ws);
    lstm_main<<<B_TOT / MB, 256, 0, stream>>>(x, hid, cel, Wih0, ws, nst, outp);
}